// Round 1
// baseline (255.351 us; speedup 1.0000x reference)
//
#include <hip/hip_runtime.h>

// GraphPositionalEncoding: degree-table PE + k-step return probabilities.
//
// Key reformulation: T = A·D^{-1} (column-normalized symmetric adjacency) is
// similar to S = D^{-1/2} A D^{-1/2} (symmetric), so diag(T^k) = diag(S^k) and
// with y_m := D^{-1} T^m e_i :
//   y_{m+1}[r] = dinv[r] * sum_{c in N(r)} y_m[c]
//   diag(T^{2m})[i]   = deg_i * sum_r deg_r * y_m[r]^2
//   diag(T^{2m+1})[i] = deg_i * sum_r deg_r * y_m[r] * y_{m+1}[r]
// -> only y_1..y_4 needed for K=8, and y_1 falls directly out of the adjacency.

#define NPG   256   // nodes per graph
#define HID   256   // hidden dim
#define KD    8     // random-walk dim
#define CCH   16    // start-node columns per block
#define YST   20    // y-panel row stride in floats (16 cols + 4 pad) = 80 B, 16B-aligned
#define CHUNKS (NPG / CCH)

__global__ __launch_bounds__(256) void k_indeg(const int* __restrict__ dst,
                                               int* __restrict__ deg, int nE) {
    int e = blockIdx.x * 256 + threadIdx.x;
    if (e < nE) atomicAdd(deg + dst[e], 1);
}

__global__ __launch_bounds__(256) void k_rw(const int* __restrict__ ei, int epg, int nE,
                                            float* __restrict__ rw_pe) {
    __shared__ unsigned int bits[NPG * 8];          // symmetric adjacency bitmask
    __shared__ float degf[NPG];
    __shared__ float dinv[NPG];
    __shared__ __align__(16) float ybuf[2][NPG * YST];
    __shared__ float dotc[4][CCH];                  // k = 1,3,5,7 (cross dots)
    __shared__ float dotsq[4][CCH];                 // k = 2,4,6,8 (square dots)

    const int g    = blockIdx.x / CHUNKS;
    const int base = (blockIdx.x % CHUNKS) * CCH;
    const int t    = threadIdx.x;                   // == row id (256 rows)

    #pragma unroll
    for (int w = 0; w < 8; ++w) bits[t * 8 + w] = 0u;
    if (t < 4 * CCH) { dotc[t >> 4][t & (CCH - 1)] = 0.f; dotsq[t >> 4][t & (CCH - 1)] = 0.f; }
    __syncthreads();

    // build symmetrized adjacency bitmask from this graph's contiguous edge slice
    const int* sp = ei + (size_t)g * epg;
    const int* dp = ei + (size_t)nE + (size_t)g * epg;
    for (int e = t; e < epg; e += 256) {
        int ls = sp[e] & (NPG - 1);
        int ld = dp[e] & (NPG - 1);
        atomicOr(&bits[ls * 8 + (ld >> 5)], 1u << (ld & 31));
        atomicOr(&bits[ld * 8 + (ls >> 5)], 1u << (ls & 31));
    }
    __syncthreads();

    int dg = 0;
    #pragma unroll
    for (int w = 0; w < 8; ++w) dg += __popc(bits[t * 8 + w]);
    degf[t] = (float)dg;
    const float di = dg ? 1.0f / (float)dg : 0.f;
    dinv[t] = di;
    __syncthreads();

    // y1 directly from adjacency: y1[r][j] = adj(r, base+j) * dinv[r] * dinv[base+j]
    {
        unsigned int word = bits[t * 8 + (base >> 5)] >> (base & 31);
        float* y1 = ybuf[0] + t * YST;
        #pragma unroll
        for (int j = 0; j < CCH; ++j)
            y1[j] = ((word >> j) & 1u) ? di * dinv[base + j] : 0.f;
    }
    __syncthreads();

    // dot slot 0: k1 = y1[base+j][j] (delta start collapses the cross dot); k2 = sum_r deg_r y1^2
    {
        const float* y1 = ybuf[0];
        int j = t & (CCH - 1), r0b = (t / CCH) * CCH;
        float ps = 0.f;
        #pragma unroll
        for (int ri = 0; ri < CCH; ++ri) {
            int r = r0b + ri;
            float v = y1[r * YST + j];
            ps += degf[r] * v * v;
        }
        atomicAdd(&dotsq[0][j], ps);
        if (t < CCH) dotc[0][t] = y1[(base + t) * YST + t];
    }
    // no barrier needed here: matvec below only reads ybuf[0]/bits, writes ybuf[1]

    int cur = 0;
    for (int mm = 1; mm <= 3; ++mm) {
        const float* yo = ybuf[cur];
        float* yn = ybuf[cur ^ 1];
        float4 a0 = make_float4(0.f, 0.f, 0.f, 0.f), a1 = a0, a2 = a0, a3 = a0;
        #pragma unroll
        for (int w = 0; w < 8; ++w) {
            unsigned int word = bits[t * 8 + w];
            while (word) {
                int c = (w << 5) + __ffs(word) - 1;
                word &= word - 1;
                const float4* row = reinterpret_cast<const float4*>(yo + c * YST);
                float4 r0 = row[0], r1 = row[1], r2 = row[2], r3 = row[3];
                a0.x += r0.x; a0.y += r0.y; a0.z += r0.z; a0.w += r0.w;
                a1.x += r1.x; a1.y += r1.y; a1.z += r1.z; a1.w += r1.w;
                a2.x += r2.x; a2.y += r2.y; a2.z += r2.z; a2.w += r2.w;
                a3.x += r3.x; a3.y += r3.y; a3.z += r3.z; a3.w += r3.w;
            }
        }
        float4* nr = reinterpret_cast<float4*>(yn + t * YST);
        nr[0] = make_float4(a0.x * di, a0.y * di, a0.z * di, a0.w * di);
        nr[1] = make_float4(a1.x * di, a1.y * di, a1.z * di, a1.w * di);
        nr[2] = make_float4(a2.x * di, a2.y * di, a2.z * di, a2.w * di);
        nr[3] = make_float4(a3.x * di, a3.y * di, a3.z * di, a3.w * di);
        __syncthreads();

        {
            int j = t & (CCH - 1), r0b = (t / CCH) * CCH;
            float pc = 0.f, ps = 0.f;
            #pragma unroll
            for (int ri = 0; ri < CCH; ++ri) {
                int r = r0b + ri;
                float d = degf[r];
                float vo = yo[r * YST + j];
                float vn = yn[r * YST + j];
                pc += d * vo * vn;
                ps += d * vn * vn;
            }
            atomicAdd(&dotc[mm][j], pc);
            atomicAdd(&dotsq[mm][j], ps);
        }
        cur ^= 1;
        __syncthreads();
    }

    if (t < CCH) {
        int i = g * NPG + base + t;
        float dii = degf[base + t];
        float4 o0 = make_float4(dii * dotc[0][t], dii * dotsq[0][t],
                                dii * dotc[1][t], dii * dotsq[1][t]);
        float4 o1 = make_float4(dii * dotc[2][t], dii * dotsq[2][t],
                                dii * dotc[3][t], dii * dotsq[3][t]);
        float4* dst = reinterpret_cast<float4*>(rw_pe + (size_t)i * KD);
        dst[0] = o0; dst[1] = o1;
    }
}

__global__ __launch_bounds__(256) void k_out(const float* __restrict__ table,
                                             const float* __restrict__ w,
                                             const float* __restrict__ b,
                                             const float* __restrict__ rw_pe,
                                             const int* __restrict__ degin,
                                             float* __restrict__ out, int nNodes) {
    int gt = blockIdx.x * 256 + threadIdx.x;
    int i = gt >> 6;
    if (i >= nNodes) return;
    int h = (gt & 63) << 2;
    int dg = degin[i]; dg = dg < 255 ? dg : 255;   // clip to MAX_NODES-1
    float4 pe = *reinterpret_cast<const float4*>(table + (size_t)dg * HID + h);
    float4 r0 = *reinterpret_cast<const float4*>(rw_pe + (size_t)i * KD);
    float4 r1 = *reinterpret_cast<const float4*>(rw_pe + (size_t)i * KD + 4);
    float4 bb = *reinterpret_cast<const float4*>(b + h);
    float s[4];
    #pragma unroll
    for (int c = 0; c < 4; ++c) {
        const float* wr = w + (size_t)(h + c) * KD;
        float4 w0 = *reinterpret_cast<const float4*>(wr);
        float4 w1 = *reinterpret_cast<const float4*>(wr + 4);
        s[c] = r0.x * w0.x + r0.y * w0.y + r0.z * w0.z + r0.w * w0.w +
               r1.x * w1.x + r1.y * w1.y + r1.z * w1.z + r1.w * w1.w;
    }
    float4 res = make_float4(pe.x + s[0] + bb.x, pe.y + s[1] + bb.y,
                             pe.z + s[2] + bb.z, pe.w + s[3] + bb.w);
    *reinterpret_cast<float4*>(out + (size_t)i * HID + h) = res;
}

extern "C" void kernel_launch(void* const* d_in, const int* in_sizes, int n_in,
                              void* d_out, int out_size, void* d_ws, size_t ws_size,
                              hipStream_t stream) {
    const int* ei      = (const int*)d_in[1];    // edge_index [2, nE]
    const float* table = (const float*)d_in[3];  // degree_table [256,256]
    const float* rw_w  = (const float*)d_in[4];  // [HID, KD]
    const float* rw_b  = (const float*)d_in[5];  // [HID]
    float* out         = (float*)d_out;

    const int nNodes = in_sizes[2];              // batch length = B*256
    const int nE     = in_sizes[1] / 2;          // total directed edges
    const int B      = nNodes / NPG;
    const int epg    = nE / B;                   // edges per graph (contiguous slices)

    int* degin   = (int*)d_ws;
    size_t off   = ((size_t)nNodes * sizeof(int) + 255) & ~(size_t)255;
    float* rw_pe = (float*)((char*)d_ws + off);  // [nNodes, KD] scratch

    hipMemsetAsync(degin, 0, (size_t)nNodes * sizeof(int), stream);
    k_indeg<<<(nE + 255) / 256, 256, 0, stream>>>(ei + nE, degin, nE);
    k_rw<<<B * CHUNKS, 256, 0, stream>>>(ei, epg, nE, rw_pe);
    const int nq = nNodes * (HID / 4);
    k_out<<<(nq + 255) / 256, 256, 0, stream>>>(table, rw_w, rw_b, rw_pe, degin, out, nNodes);
}

// Round 2
// 189.199 us; speedup vs baseline: 1.3496x; 1.3496x over previous
//
#include <hip/hip_runtime.h>

// GraphPositionalEncoding: degree-table PE + k-step return probabilities.
//
// Symmetric reformulation: T = A D^{-1} is similar to S = D^{-1/2} A D^{-1/2},
// so diag(T^k) = diag(S^k). With stored panel P_m := D^{-1/2} S^m E_J (J = 128
// start columns) and W := A * P_m (0/1 adjacency, exact in fp16 -> MFMA):
//   P_{m+1} = dinv ∘ W
//   diag(S^{2m})  [j] = sum_r deg_r P_m[r,j]^2
//   diag(S^{2m+1})[j] = sum_r P_m[r,j] * W[r,j]          (deg*dinv = 1 or row=0)
//   diag(S^{2m+2})[j] = sum_r dinv_r * W[r,j]^2
// K=8 needs only P_1..P_3 and 3 MFMA matmuls of 256x256x128 per block.

#define NPG 256
#define HID 256
#define KD  8

typedef _Float16 f16x8 __attribute__((ext_vector_type(8)));
typedef float f32x4 __attribute__((ext_vector_type(4)));

union U4H8 { unsigned int u[4]; uint4 u4; f16x8 h; _Float16 hh[8]; };
union U2H4 { unsigned int u[2]; uint2 u2; _Float16 h[4]; };

__global__ __launch_bounds__(256) void k_indeg(const int* __restrict__ dst,
                                               int* __restrict__ deg, int nE) {
    int e = blockIdx.x * 256 + threadIdx.x;
    if (e < nE) atomicAdd(deg + dst[e], 1);
}

__global__ __launch_bounds__(512, 4) void k_rw2(const int* __restrict__ ei, int epg, int nE,
                                                float* __restrict__ rw_pe) {
    __shared__ unsigned int bits[NPG * 8];            // 8 KB symmetric adjacency bitmask
    __shared__ float diA[NPG];                        // 1/deg
    __shared__ float sA[NPG];                         // 1/sqrt(deg)
    __shared__ __align__(16) _Float16 Zt[128 * 256];  // 64 KB P panel, [j][c], slot-swizzled
    __shared__ float dots[KD][128];                   // k1..k8 per local column

    const int g    = blockIdx.x >> 1;
    const int jb   = (blockIdx.x & 1) << 7;           // column-half base
    const int t    = threadIdx.x;
    const int lane = t & 63;
    const int wid  = t >> 6;                          // 8 waves
    const int wr   = wid >> 1;                        // 0..3 row-group
    const int wj   = wid & 1;                         // 0..1 col-group
    const int l15  = lane & 15;
    const int q    = lane >> 4;                       // 0..3 quarter

    #pragma unroll
    for (int i = 0; i < 4; ++i) bits[t + 512 * i] = 0u;
    ((float*)dots)[t] = 0.f;
    ((float*)dots)[t + 512] = 0.f;
    __syncthreads();

    // build symmetrized adjacency from this graph's contiguous edge slice
    const int* sp = ei + (size_t)g * epg;
    const int* dp = ei + (size_t)nE + (size_t)g * epg;
    for (int e = t; e < epg; e += 512) {
        int ls = sp[e] & (NPG - 1);
        int ld = dp[e] & (NPG - 1);
        atomicOr(&bits[ls * 8 + (ld >> 5)], 1u << (ld & 31));
        atomicOr(&bits[ld * 8 + (ls >> 5)], 1u << (ls & 31));
    }
    __syncthreads();

    if (t < NPG) {
        int dg = 0;
        #pragma unroll
        for (int w = 0; w < 8; ++w) dg += __popc(bits[t * 8 + w]);
        float di = dg ? 1.f / (float)dg : 0.f;
        diA[t] = di;
        sA[t]  = sqrtf(di);
    }
    __syncthreads();

    // ---- build P1[c,j] = dinv_c * s_j * a(c,j) into Zt; accumulate k2 ----
    #pragma unroll
    for (int pass = 0; pass < 2; ++pass) {
        int tau = t + pass * 512;
        int j = tau & 127, w = tau >> 7;
        int jg = jb + j;
        unsigned word = bits[jg * 8 + w];
        float sj = sA[jg], dij = diA[jg];
        float accd = 0.f;
        #pragma unroll
        for (int sl = 0; sl < 4; ++sl) {
            int c0 = w * 32 + sl * 8;
            unsigned byte = (word >> (sl * 8)) & 0xFFu;
            float4 d0 = *(const float4*)(diA + c0);
            float4 d1 = *(const float4*)(diA + c0 + 4);
            float dv0 = (byte & 1u)   ? d0.x : 0.f;
            float dv1 = (byte & 2u)   ? d0.y : 0.f;
            float dv2 = (byte & 4u)   ? d0.z : 0.f;
            float dv3 = (byte & 8u)   ? d0.w : 0.f;
            float dv4 = (byte & 16u)  ? d1.x : 0.f;
            float dv5 = (byte & 32u)  ? d1.y : 0.f;
            float dv6 = (byte & 64u)  ? d1.z : 0.f;
            float dv7 = (byte & 128u) ? d1.w : 0.f;
            accd += dv0 + dv1 + dv2 + dv3 + dv4 + dv5 + dv6 + dv7;
            U4H8 u;
            u.hh[0] = (_Float16)(dv0 * sj); u.hh[1] = (_Float16)(dv1 * sj);
            u.hh[2] = (_Float16)(dv2 * sj); u.hh[3] = (_Float16)(dv3 * sj);
            u.hh[4] = (_Float16)(dv4 * sj); u.hh[5] = (_Float16)(dv5 * sj);
            u.hh[6] = (_Float16)(dv6 * sj); u.hh[7] = (_Float16)(dv7 * sj);
            int slp = (w * 4 + sl) ^ (j & 7);
            *(uint4*)(Zt + j * 256 + slp * 8) = u.u4;
        }
        atomicAdd(&dots[1][j], dij * accd);   // k2 = dinv_j * sum_c dinv_c a(c,j)
    }
    if (t < 128) {                            // k1 = dinv_j if self-loop
        int jg = jb + t;
        unsigned selfb = (bits[jg * 8 + (jg >> 5)] >> (jg & 31)) & 1u;
        dots[0][t] = selfb ? diA[jg] : 0.f;
    }

    // per-lane packed A bytes: ab[ks] holds bytes (8 k-bits) for rr = 0..3
    unsigned ab[8];
    #pragma unroll
    for (int ks = 0; ks < 8; ++ks) {
        unsigned v = 0;
        #pragma unroll
        for (int rr = 0; rr < 4; ++rr) {
            int r = (wr * 4 + rr) * 16 + l15;
            v |= ((bits[r * 8 + ks] >> (q * 8)) & 0xFFu) << (rr * 8);
        }
        ab[ks] = v;
    }
    __syncthreads();

    // ---- 3 MFMA steps ----
    for (int mm = 1; mm <= 3; ++mm) {
        f32x4 acc[4][4];
        #pragma unroll
        for (int rr = 0; rr < 4; ++rr)
            #pragma unroll
            for (int jj = 0; jj < 4; ++jj)
                acc[rr][jj] = (f32x4){0.f, 0.f, 0.f, 0.f};

        #pragma unroll
        for (int ks = 0; ks < 8; ++ks) {
            f16x8 af[4];
            #pragma unroll
            for (int rr = 0; rr < 4; ++rr) {
                unsigned byte = (ab[ks] >> (rr * 8)) & 0xFFu;
                U4H8 u;
                #pragma unroll
                for (int p = 0; p < 4; ++p)
                    u.u[p] = (((byte >> (2 * p)) & 1u) ? 0x3C00u : 0u) |
                             (((byte >> (2 * p + 1)) & 1u) ? 0x3C000000u : 0u);
                af[rr] = u.h;
            }
            #pragma unroll
            for (int jj = 0; jj < 4; ++jj) {
                int jloc = wj * 64 + jj * 16 + l15;
                int slp = (ks * 4 + q) ^ (jloc & 7);
                U4H8 b;
                b.u4 = *(const uint4*)(Zt + jloc * 256 + slp * 8);
                #pragma unroll
                for (int rr = 0; rr < 4; ++rr)
                    acc[rr][jj] = __builtin_amdgcn_mfma_f32_16x16x32_f16(af[rr], b.h, acc[rr][jj], 0, 0, 0);
            }
        }

        // dots (read old P before overwrite) + stage new P in regs
        float cross[4] = {0.f, 0.f, 0.f, 0.f}, sq[4] = {0.f, 0.f, 0.f, 0.f};
        uint2 np[4][4];
        #pragma unroll
        for (int rr = 0; rr < 4; ++rr) {
            int r0 = (wr * 4 + rr) * 16 + q * 4;
            float4 di4 = *(const float4*)(diA + r0);
            #pragma unroll
            for (int jj = 0; jj < 4; ++jj) {
                int jloc = wj * 64 + jj * 16 + l15;
                int slp = ((wr * 4 + rr) * 2 + (q >> 1)) ^ (jloc & 7);
                const _Float16* ap = Zt + jloc * 256 + slp * 8 + (q & 1) * 4;
                U2H4 old; old.u2 = *(const uint2*)ap;
                f32x4 W = acc[rr][jj];
                cross[jj] += (float)old.h[0] * W[0] + (float)old.h[1] * W[1] +
                             (float)old.h[2] * W[2] + (float)old.h[3] * W[3];
                sq[jj] += di4.x * W[0] * W[0] + di4.y * W[1] * W[1] +
                          di4.z * W[2] * W[2] + di4.w * W[3] * W[3];
                U2H4 nw;
                nw.h[0] = (_Float16)(di4.x * W[0]); nw.h[1] = (_Float16)(di4.y * W[1]);
                nw.h[2] = (_Float16)(di4.z * W[2]); nw.h[3] = (_Float16)(di4.w * W[3]);
                np[rr][jj] = nw.u2;
            }
        }
        #pragma unroll
        for (int jj = 0; jj < 4; ++jj) {
            int jloc = wj * 64 + jj * 16 + l15;
            atomicAdd(&dots[2 * mm][jloc], cross[jj]);
            atomicAdd(&dots[2 * mm + 1][jloc], sq[jj]);
        }
        if (mm < 3) {
            __syncthreads();    // all reads of P_m done -> safe to overwrite
            #pragma unroll
            for (int rr = 0; rr < 4; ++rr)
                #pragma unroll
                for (int jj = 0; jj < 4; ++jj) {
                    int jloc = wj * 64 + jj * 16 + l15;
                    int slp = ((wr * 4 + rr) * 2 + (q >> 1)) ^ (jloc & 7);
                    *(uint2*)(Zt + jloc * 256 + slp * 8 + (q & 1) * 4) = np[rr][jj];
                }
            __syncthreads();
        }
    }
    __syncthreads();

    if (t < 128) {
        size_t node = (size_t)g * NPG + jb + t;
        float4 o0 = make_float4(dots[0][t], dots[1][t], dots[2][t], dots[3][t]);
        float4 o1 = make_float4(dots[4][t], dots[5][t], dots[6][t], dots[7][t]);
        ((float4*)(rw_pe + node * KD))[0] = o0;
        ((float4*)(rw_pe + node * KD))[1] = o1;
    }
}

__global__ __launch_bounds__(256) void k_out(const float* __restrict__ table,
                                             const float* __restrict__ w,
                                             const float* __restrict__ b,
                                             const float* __restrict__ rw_pe,
                                             const int* __restrict__ degin,
                                             float* __restrict__ out, int nNodes) {
    int gt = blockIdx.x * 256 + threadIdx.x;
    int i = gt >> 6;
    if (i >= nNodes) return;
    int h = (gt & 63) << 2;
    int dg = degin[i]; dg = dg < 255 ? dg : 255;
    float4 pe = *reinterpret_cast<const float4*>(table + (size_t)dg * HID + h);
    float4 r0 = *reinterpret_cast<const float4*>(rw_pe + (size_t)i * KD);
    float4 r1 = *reinterpret_cast<const float4*>(rw_pe + (size_t)i * KD + 4);
    float4 bb = *reinterpret_cast<const float4*>(b + h);
    float s[4];
    #pragma unroll
    for (int c = 0; c < 4; ++c) {
        const float* wr = w + (size_t)(h + c) * KD;
        float4 w0 = *reinterpret_cast<const float4*>(wr);
        float4 w1 = *reinterpret_cast<const float4*>(wr + 4);
        s[c] = r0.x * w0.x + r0.y * w0.y + r0.z * w0.z + r0.w * w0.w +
               r1.x * w1.x + r1.y * w1.y + r1.z * w1.z + r1.w * w1.w;
    }
    float4 res = make_float4(pe.x + s[0] + bb.x, pe.y + s[1] + bb.y,
                             pe.z + s[2] + bb.z, pe.w + s[3] + bb.w);
    *reinterpret_cast<float4*>(out + (size_t)i * HID + h) = res;
}

extern "C" void kernel_launch(void* const* d_in, const int* in_sizes, int n_in,
                              void* d_out, int out_size, void* d_ws, size_t ws_size,
                              hipStream_t stream) {
    const int* ei      = (const int*)d_in[1];
    const float* table = (const float*)d_in[3];
    const float* rw_w  = (const float*)d_in[4];
    const float* rw_b  = (const float*)d_in[5];
    float* out         = (float*)d_out;

    const int nNodes = in_sizes[2];
    const int nE     = in_sizes[1] / 2;
    const int B      = nNodes / NPG;
    const int epg    = nE / B;

    int* degin   = (int*)d_ws;
    size_t off   = ((size_t)nNodes * sizeof(int) + 255) & ~(size_t)255;
    float* rw_pe = (float*)((char*)d_ws + off);

    hipMemsetAsync(degin, 0, (size_t)nNodes * sizeof(int), stream);
    k_indeg<<<(nE + 255) / 256, 256, 0, stream>>>(ei + nE, degin, nE);
    k_rw2<<<B * 2, 512, 0, stream>>>(ei, epg, nE, rw_pe);
    const int nq = nNodes * (HID / 4);
    k_out<<<(nq + 255) / 256, 256, 0, stream>>>(table, rw_w, rw_b, rw_pe, degin, out, nNodes);
}